// Round 3
// baseline (241.805 us; speedup 1.0000x reference)
//
#include <hip/hip_runtime.h>
#include <stdint.h>

#define NTOK   8192
#define DIM    1024
#define NEXP   8
#define MAXP   8192

typedef float    f32x4  __attribute__((ext_vector_type(4)));
typedef __bf16   bf16x8 __attribute__((ext_vector_type(8)));
typedef _Float16 h16x8  __attribute__((ext_vector_type(8)));

typedef __attribute__((address_space(1))) const void* gas_ptr;
typedef __attribute__((address_space(3))) void*       las_ptr;

__device__ __forceinline__ unsigned short f32_to_bf16(float f) {
  union { float f; unsigned int u; } v; v.f = f;
  unsigned int u = v.u;
  unsigned int r = (u + 0x7FFFu + ((u >> 16) & 1u)) >> 16;
  return (unsigned short)r;
}

// ---------------------------------------------------------------------------
// Fused prep (unchanged).
// Blocks [0,2048): We[e][d][h] fp32 -> Wf bf16 TILE-LINEAR:
//   block (e,nt,kt) = 4096 elems (128 n-rows x 32 k), element offset
//   ((e*8+nt)*32 + kt)*4096 + n_local*32 + k_local.
//   This is exactly one 32-k half-tile column group of the BK=64 GEMM.
// Blocks [2048,2560): gate scores, 4 tokens/wave, fp64; also x->bf16.
// ---------------------------------------------------------------------------
__global__ __launch_bounds__(256) void prep_kernel(
    const float* __restrict__ We, unsigned short* __restrict__ Wf,
    const float* __restrict__ x, const float* __restrict__ Wg,
    const float* __restrict__ bg, unsigned short* __restrict__ Xbf,
    int* __restrict__ tok_ee, float2* __restrict__ tok_w) {
  __shared__ float tile[64][65];
  const int bid = blockIdx.x;
  if (bid < 2048) {
    const int e  = bid >> 8;
    const int d0 = ((bid >> 4) & 15) * 64;
    const int h0 = (bid & 15) * 64;
    const int t  = threadIdx.x;
    const int tx = t & 63, ty = t >> 6;
    const float* src = We + (size_t)e * DIM * DIM;
#pragma unroll
    for (int i = 0; i < 16; ++i) {
      int d = ty + i * 4;
      tile[d][tx] = src[(size_t)(d0 + d) * DIM + (h0 + tx)];
    }
    __syncthreads();
    const int nt    = h0 >> 7;
    const int rbase = h0 & 64;
    const int hl    = t >> 2;
    const int k8    = t & 3;
#pragma unroll
    for (int reg = 0; reg < 2; ++reg) {
      const int kt = (d0 >> 5) + reg;
      unsigned int pk[4];
#pragma unroll
      for (int q = 0; q < 4; ++q) {
        int dl = reg * 32 + k8 * 8 + q * 2;
        pk[q] = (unsigned int)f32_to_bf16(tile[dl][hl]) |
                ((unsigned int)f32_to_bf16(tile[dl + 1][hl]) << 16);
      }
      size_t base = (((size_t)(e * 8 + nt) * 32 + kt) << 12) +
                    (size_t)(rbase + hl) * 32 + k8 * 8;
      *(uint4*)&Wf[base] = make_uint4(pk[0], pk[1], pk[2], pk[3]);
    }
    return;
  }
  // ---- gate scores: 4 tokens per wave ----
  const int blk  = bid - 2048;
  const int wave = threadIdx.x >> 6;
  const int lane = threadIdx.x & 63;
  const int tok0 = blk * 16 + wave * 4;

  float xs[4][16];
#pragma unroll
  for (int t = 0; t < 4; ++t) {
    const float* xr = x + (size_t)(tok0 + t) * DIM + lane * 16;
#pragma unroll
    for (int i = 0; i < 4; ++i)
      *(f32x4*)&xs[t][i * 4] = *(const f32x4*)(xr + i * 4);
  }
#pragma unroll
  for (int t = 0; t < 4; ++t) {
    unsigned int pk[8];
#pragma unroll
    for (int i = 0; i < 8; ++i)
      pk[i] = (unsigned int)f32_to_bf16(xs[t][2 * i]) |
              ((unsigned int)f32_to_bf16(xs[t][2 * i + 1]) << 16);
    uint4* xb = (uint4*)(Xbf + (size_t)(tok0 + t) * DIM + lane * 16);
    xb[0] = make_uint4(pk[0], pk[1], pk[2], pk[3]);
    xb[1] = make_uint4(pk[4], pk[5], pk[6], pk[7]);
  }

  double acc[4][8];
#pragma unroll
  for (int t = 0; t < 4; ++t)
#pragma unroll
    for (int e = 0; e < 8; ++e) acc[t][e] = 0.0;

  const float* wr = Wg + (size_t)(lane * 16) * NEXP;
#pragma unroll
  for (int i = 0; i < 16; ++i) {
    f32x4 wa = *(const f32x4*)(wr + i * 8);
    f32x4 wb = *(const f32x4*)(wr + i * 8 + 4);
    double w0 = wa[0], w1 = wa[1], w2 = wa[2], w3 = wa[3];
    double w4 = wb[0], w5 = wb[1], w6 = wb[2], w7 = wb[3];
#pragma unroll
    for (int t = 0; t < 4; ++t) {
      double xd = (double)xs[t][i];
      acc[t][0] += xd * w0; acc[t][1] += xd * w1;
      acc[t][2] += xd * w2; acc[t][3] += xd * w3;
      acc[t][4] += xd * w4; acc[t][5] += xd * w5;
      acc[t][6] += xd * w6; acc[t][7] += xd * w7;
    }
  }
#pragma unroll
  for (int m = 1; m < 64; m <<= 1)
#pragma unroll
    for (int t = 0; t < 4; ++t)
#pragma unroll
      for (int e = 0; e < 8; ++e) acc[t][e] += __shfl_xor(acc[t][e], m, 64);

  if (lane == 0) {
#pragma unroll
    for (int t = 0; t < 4; ++t) {
      float s[8];
#pragma unroll
      for (int e = 0; e < 8; ++e) s[e] = (float)acc[t][e] + bg[e];
      int i0 = 0; float v0 = s[0];
#pragma unroll
      for (int e = 1; e < 8; ++e) if (s[e] > v0) { v0 = s[e]; i0 = e; }
      int i1 = -1; float v1 = -3.4e38f;
#pragma unroll
      for (int e = 0; e < 8; ++e) if (e != i0 && s[e] > v1) { v1 = s[e]; i1 = e; }
      float t1 = expf(v1 - v0);
      float den = 1.0f + t1;
      tok_ee[tok0 + t] = i0 | (i1 << 8);
      tok_w[tok0 + t]  = make_float2(1.0f / den, t1 / den);
    }
  }
}

// ---------------------------------------------------------------------------
// Parallel deterministic compaction (unchanged).
// ---------------------------------------------------------------------------
__global__ __launch_bounds__(1024) void compact_kernel(
    const int* __restrict__ tok_ee, const float2* __restrict__ tok_w,
    int* __restrict__ counts, int* __restrict__ pair_token,
    float* __restrict__ pair_w) {
  __shared__ int wave_cnt[16];
  __shared__ int wave_off[16];
  const int e = blockIdx.x;
  const int tid = threadIdx.x, wave = tid >> 6, lane = tid & 63;
  int base = 0;
  for (int c = 0; c < NTOK / 1024; ++c) {
    const int t = c * 1024 + tid;
    const int p = tok_ee[t];
    const bool m0 = ((p & 255) == e);
    const bool m1 = (((p >> 8) & 255) == e);
    const unsigned long long m = __ballot(m0 || m1);
    const int pre = __popcll(m & ((1ull << lane) - 1ull));
    if (lane == 0) wave_cnt[wave] = __popcll(m);
    __syncthreads();
    if (tid == 0) {
      int s = base;
      for (int w = 0; w < 16; ++w) { wave_off[w] = s; s += wave_cnt[w]; }
      base = s;
    }
    __syncthreads();
    if (m0 || m1) {
      const float2 w = tok_w[t];
      const int slot = wave_off[wave] + pre;
      pair_token[e * MAXP + slot] = (t << 1) | (m1 ? 1 : 0);
      pair_w[e * MAXP + slot]     = m1 ? w.y : w.x;
    }
    __syncthreads();
  }
  if (tid == 0) counts[e] = base;
}

// ---------------------------------------------------------------------------
// Grouped GEMM — 256x256 tile, BK=64, 8 waves, 8-phase-per-2-K-tiles schedule
// (T3+T4 counted vmcnt, T2 swizzle, T5 setprio). 2 LDS buffers of
// (A 256x64 + B 256x64) bf16, stored as K-split half-tiles [256 rows][32 k]
// (64B rows). Stages always target the buffer NOT being read (no intra-quad
// WAR). vmcnt(4) before the closing barrier of phases 2 and 4 leaves exactly
// the newest half-tile pair in flight across barriers; never 0 in the loop.
// Chunk swizzle (proven 0-conflict in R1): src chunk ^= (lane>>3)&3, read
// chunk = fq ^ ((fm>>1)&3).
// ---------------------------------------------------------------------------
#define BARC()                                  \
  { asm volatile("" ::: "memory");              \
    __builtin_amdgcn_s_barrier();               \
    asm volatile("" ::: "memory"); }

__global__ __launch_bounds__(512, 2) void moe_gemm(
    const unsigned short* __restrict__ Xbf, const unsigned short* __restrict__ Wf,
    const float* __restrict__ be, const int* __restrict__ counts,
    const int* __restrict__ pair_token, const float* __restrict__ pair_w,
    _Float16* __restrict__ part, float* __restrict__ Y, int use_part) {
  const int id    = blockIdx.x;
  const int e     = id & 7;                 // expert -> XCD
  const int ntile = (id >> 3) & 3;          // 256-col tile
  const int m0    = (id >> 5) * 256;
  const int cnt   = counts[e];
  if (m0 >= cnt) return;

  __shared__ __align__(16) unsigned short As[2][2][256 * 32];  // [buf][ks]
  __shared__ __align__(16) unsigned short Bs[2][2][256 * 32];

  const int tid  = threadIdx.x;
  const int wave = tid >> 6;                // 0..7
  const int lane = tid & 63;
  const int fm   = lane & 15;
  const int fq   = lane >> 4;
  const int wm   = wave >> 2;               // 0..1 (M half)
  const int wn   = wave & 3;                // 0..3 (N quarter)

  // staging source chunk swizzle (R1-proven, 0 conflicts)
  const int kc = (((lane & 3) ^ ((lane >> 3) & 3)) * 8);
  const unsigned short* gA[2];
  const unsigned short* gB[2];
#pragma unroll
  for (int l = 0; l < 2; ++l) {
    const int R  = wave * 2 + l;            // 16-row group 0..15
    const int gr = m0 + R * 16 + (lane >> 2);
    const int tk = (gr < cnt) ? (pair_token[e * MAXP + gr] >> 1) : 0;
    gA[l] = Xbf + (size_t)tk * DIM + kc;
    gB[l] = Wf + ((size_t)(e * 8 + ntile * 2 + (R >> 3)) << 17) +
            (size_t)((R & 7) * 16 + (lane >> 2)) * 32 + kc;
  }

  // stage half-tile (16KB): per wave 2 x 1KB lds-linear writes
#define STAGE_A(buf, ksv, ttv)                                                \
  { _Pragma("unroll") for (int l = 0; l < 2; ++l)                             \
      __builtin_amdgcn_global_load_lds(                                       \
          (gas_ptr)(uintptr_t)(gA[l] + (ttv) * 64 + (ksv) * 32),              \
          (las_ptr)(uintptr_t)(&As[buf][ksv][(wave * 2 + l) * 512]), 16, 0, 0); }
#define STAGE_B(buf, ksv, ttv)                                                \
  { _Pragma("unroll") for (int l = 0; l < 2; ++l)                             \
      __builtin_amdgcn_global_load_lds(                                       \
          (gas_ptr)(uintptr_t)(gB[l] + (size_t)((ttv) * 2 + (ksv)) * 4096),   \
          (las_ptr)(uintptr_t)(&Bs[buf][ksv][(wave * 2 + l) * 512]), 16, 0, 0); }

  f32x4 acc[8][4];
#pragma unroll
  for (int i = 0; i < 8; ++i)
#pragma unroll
    for (int j = 0; j < 4; ++j) { f32x4 z = {0.f, 0.f, 0.f, 0.f}; acc[i][j] = z; }

  // swizzled ds_read chunk; row bases (row*32 elems, 64B rows)
  const int rdo  = (fq ^ ((fm >> 1) & 3)) * 8;
  const int arow = (wm * 128 + fm) * 32 + rdo;    // + i*512
  const int brow = (wn * 64 + fm) * 32 + rdo;     // + jh*1024 + j2*512

#define MFMA16(JB)                                                            \
  { _Pragma("unroll") for (int i = 0; i < 8; ++i)                             \
      _Pragma("unroll") for (int j = 0; j < 2; ++j)                           \
        acc[i][(JB) + j] = __builtin_amdgcn_mfma_f32_16x16x32_bf16(           \
            af[i], bfr[j], acc[i][(JB) + j], 0, 0, 0); }

  // prologue: tile 0 fully staged into buf 0, drained (covers pair_token too)
  STAGE_A(0, 0, 0); STAGE_B(0, 0, 0); STAGE_A(0, 1, 0); STAGE_B(0, 1, 0);
  asm volatile("s_waitcnt vmcnt(0)" ::: "memory");
  BARC();

#pragma unroll 2
  for (int t = 0; t < 16; ++t) {
    const int p  = t & 1;
    const int q  = p ^ 1;
    const int tt = (t + 1) & 15;            // dummy re-stage at t=15
    bf16x8 af[8], bfr[2];

    // ---- phase 1: (ks0, jh0); stage A-klo(t+1) -> q ----
#pragma unroll
    for (int i = 0; i < 8; ++i) af[i] = *(const bf16x8*)&As[p][0][arow + i * 512];
#pragma unroll
    for (int j = 0; j < 2; ++j) bfr[j] = *(const bf16x8*)&Bs[p][0][brow + j * 512];
    STAGE_A(q, 0, tt);
    BARC();
    asm volatile("s_waitcnt lgkmcnt(0)" ::: "memory");
    __builtin_amdgcn_sched_barrier(0);
    __builtin_amdgcn_s_setprio(1);
    MFMA16(0);
    __builtin_amdgcn_s_setprio(0);
    BARC();

    // ---- phase 2: (ks0, jh1); stage B-klo(t+1) -> q; vmcnt(4) ----
#pragma unroll
    for (int j = 0; j < 2; ++j)
      bfr[j] = *(const bf16x8*)&Bs[p][0][brow + 1024 + j * 512];
    STAGE_B(q, 0, tt);
    BARC();
    asm volatile("s_waitcnt lgkmcnt(0)" ::: "memory");
    __builtin_amdgcn_sched_barrier(0);
    __builtin_amdgcn_s_setprio(1);
    MFMA16(2);
    __builtin_amdgcn_s_setprio(0);
    asm volatile("s_waitcnt vmcnt(4)" ::: "memory");  // t's ks1 pair landed
    BARC();

    // ---- phase 3: (ks1, jh0); stage A-khi(t+1) -> q ----
#pragma unroll
    for (int i = 0; i < 8; ++i) af[i] = *(const bf16x8*)&As[p][1][arow + i * 512];
#pragma unroll
    for (int j = 0; j < 2; ++j) bfr[j] = *(const bf16x8*)&Bs[p][1][brow + j * 512];
    STAGE_A(q, 1, tt);
    BARC();
    asm volatile("s_waitcnt lgkmcnt(0)" ::: "memory");
    __builtin_amdgcn_sched_barrier(0);
    __builtin_amdgcn_s_setprio(1);
    MFMA16(0);
    __builtin_amdgcn_s_setprio(0);
    BARC();

    // ---- phase 4: (ks1, jh1); stage B-khi(t+1) -> q; vmcnt(4) ----
#pragma unroll
    for (int j = 0; j < 2; ++j)
      bfr[j] = *(const bf16x8*)&Bs[p][1][brow + 1024 + j * 512];
    STAGE_B(q, 1, tt);
    BARC();
    asm volatile("s_waitcnt lgkmcnt(0)" ::: "memory");
    __builtin_amdgcn_sched_barrier(0);
    __builtin_amdgcn_s_setprio(1);
    MFMA16(2);
    __builtin_amdgcn_s_setprio(0);
    asm volatile("s_waitcnt vmcnt(4)" ::: "memory");  // (t+1)'s ks0 pair landed
    BARC();
  }
  asm volatile("s_waitcnt vmcnt(0)" ::: "memory");    // drain dummy stages
#undef STAGE_A
#undef STAGE_B
#undef MFMA16

  // ---- epilogue ----
  int   rowv[8][4];
  float wrow[8][4];
#pragma unroll
  for (int i = 0; i < 8; ++i)
#pragma unroll
    for (int r = 0; r < 4; ++r) {
      int gr = m0 + wm * 128 + i * 16 + fq * 4 + r;
      bool valid = gr < cnt;
      rowv[i][r] = valid ? pair_token[e * MAXP + gr] : -1;
      wrow[i][r] = valid ? pair_w[e * MAXP + gr] : 0.f;
    }
  if (use_part) {
#pragma unroll
    for (int j = 0; j < 4; ++j) {
      int col = ntile * 256 + wn * 64 + j * 16 + fm;
      float bev = be[e * DIM + col];
#pragma unroll
      for (int i = 0; i < 8; ++i)
#pragma unroll
        for (int r = 0; r < 4; ++r) {
          int v = rowv[i][r];
          if (v >= 0)
            __builtin_nontemporal_store(
                (_Float16)(wrow[i][r] * (acc[i][j][r] + bev)),
                &part[(size_t)v * DIM + col]);
        }
    }
  } else {
#pragma unroll
    for (int j = 0; j < 4; ++j) {
      int col = ntile * 256 + wn * 64 + j * 16 + fm;
      float bev = be[e * DIM + col];
#pragma unroll
      for (int i = 0; i < 8; ++i)
#pragma unroll
        for (int r = 0; r < 4; ++r) {
          int v = rowv[i][r];
          if (v >= 0)
            atomicAdd(Y + (size_t)(v >> 1) * DIM + col,
                      wrow[i][r] * (acc[i][j][r] + bev));
        }
    }
  }
}

// ---------------------------------------------------------------------------
// Y[t][d] = part[2t][d] + part[2t+1][d]; fp16 in, fp32 out (unchanged).
// ---------------------------------------------------------------------------
__global__ __launch_bounds__(256) void reduce_pairs(
    const _Float16* __restrict__ part, float* __restrict__ Y) {
  const int g = blockIdx.x * 256 + threadIdx.x;
  const int t = g >> 7;
  const int o = (g & 127) * 8;
  const h16x8 a =
      __builtin_nontemporal_load((const h16x8*)(part + (size_t)(2 * t) * DIM + o));
  const h16x8 b =
      __builtin_nontemporal_load((const h16x8*)(part + (size_t)(2 * t + 1) * DIM + o));
  float* y = Y + (size_t)t * DIM + o;
  f32x4 lo = {(float)a[0] + (float)b[0], (float)a[1] + (float)b[1],
              (float)a[2] + (float)b[2], (float)a[3] + (float)b[3]};
  f32x4 hi = {(float)a[4] + (float)b[4], (float)a[5] + (float)b[5],
              (float)a[6] + (float)b[6], (float)a[7] + (float)b[7]};
  __builtin_nontemporal_store(lo, (f32x4*)y);
  __builtin_nontemporal_store(hi, (f32x4*)(y + 4));
}

// ---------------------------------------------------------------------------
extern "C" void kernel_launch(void* const* d_in, const int* in_sizes, int n_in,
                              void* d_out, int out_size, void* d_ws, size_t ws_size,
                              hipStream_t stream) {
  const float* x  = (const float*)d_in[0];
  const float* Wg = (const float*)d_in[1];
  const float* bg = (const float*)d_in[2];
  const float* We = (const float*)d_in[3];
  const float* be = (const float*)d_in[4];
  float* Y = (float*)d_out;

  const size_t MB = 1024 * 1024;
  char* ws = (char*)d_ws;
  unsigned short* Xbf = (unsigned short*)ws;                 // 16 MiB
  unsigned short* Wf  = (unsigned short*)(ws + 16 * MB);     // 16 MiB
  const size_t part_bytes = (size_t)NTOK * 2 * DIM * 2;      // 32 MiB (fp16)
  const size_t need = 32 * MB + part_bytes + 1 * MB;
  const int use_part = ws_size >= need;
  _Float16* part = (_Float16*)(ws + 32 * MB);
  char* p2 = ws + 32 * MB + (use_part ? part_bytes : 0);
  int*    counts     = (int*)p2;
  int*    pair_token = (int*)(p2 + 256);
  float*  pair_w     = (float*)(p2 + 256 + 262144);
  int*    tok_ee     = (int*)(p2 + 256 + 2 * 262144);
  float2* tok_w      = (float2*)(p2 + 256 + 2 * 262144 + 32768);

  if (!use_part)
    hipMemsetAsync(d_out, 0, (size_t)out_size * sizeof(float), stream);

  prep_kernel<<<2560, 256, 0, stream>>>(We, Wf, x, Wg, bg, Xbf, tok_ee, tok_w);
  compact_kernel<<<NEXP, 1024, 0, stream>>>(tok_ee, tok_w, counts, pair_token,
                                            pair_w);
  moe_gemm<<<8 * 4 * (MAXP / 256), 512, 0, stream>>>(
      Xbf, Wf, be, counts, pair_token, pair_w, part, Y, use_part);
  if (use_part)
    reduce_pairs<<<NTOK * DIM / 8 / 256, 256, 0, stream>>>(part, Y);
}

// Round 4
// 239.218 us; speedup vs baseline: 1.0108x; 1.0108x over previous
//
#include <hip/hip_runtime.h>
#include <stdint.h>

#define NTOK   8192
#define DIM    1024
#define NEXP   8
#define MAXP   8192

typedef float    f32x4  __attribute__((ext_vector_type(4)));
typedef __bf16   bf16x8 __attribute__((ext_vector_type(8)));
typedef _Float16 h16x8  __attribute__((ext_vector_type(8)));

typedef __attribute__((address_space(1))) const void* gas_ptr;
typedef __attribute__((address_space(3))) void*       las_ptr;

__device__ __forceinline__ unsigned short f32_to_bf16(float f) {
  union { float f; unsigned int u; } v; v.f = f;
  unsigned int u = v.u;
  unsigned int r = (u + 0x7FFFu + ((u >> 16) & 1u)) >> 16;
  return (unsigned short)r;
}

// ---------------------------------------------------------------------------
// Fused prep (unchanged).
// Blocks [0,2048): We[e][d][h] fp32 -> Wf bf16 TILE-LINEAR:
//   block (e,nt,kt) = 4096 elems (128 n-rows x 32 k), element offset
//   ((e*8+nt)*32 + kt)*4096 + n_local*32 + k_local.
// Blocks [2048,2560): gate scores, 4 tokens/wave, fp64; also x->bf16.
// ---------------------------------------------------------------------------
__global__ __launch_bounds__(256) void prep_kernel(
    const float* __restrict__ We, unsigned short* __restrict__ Wf,
    const float* __restrict__ x, const float* __restrict__ Wg,
    const float* __restrict__ bg, unsigned short* __restrict__ Xbf,
    int* __restrict__ tok_ee, float2* __restrict__ tok_w) {
  __shared__ float tile[64][65];
  const int bid = blockIdx.x;
  if (bid < 2048) {
    const int e  = bid >> 8;
    const int d0 = ((bid >> 4) & 15) * 64;
    const int h0 = (bid & 15) * 64;
    const int t  = threadIdx.x;
    const int tx = t & 63, ty = t >> 6;
    const float* src = We + (size_t)e * DIM * DIM;
#pragma unroll
    for (int i = 0; i < 16; ++i) {
      int d = ty + i * 4;
      tile[d][tx] = src[(size_t)(d0 + d) * DIM + (h0 + tx)];
    }
    __syncthreads();
    const int nt    = h0 >> 7;
    const int rbase = h0 & 64;
    const int hl    = t >> 2;
    const int k8    = t & 3;
#pragma unroll
    for (int reg = 0; reg < 2; ++reg) {
      const int kt = (d0 >> 5) + reg;
      unsigned int pk[4];
#pragma unroll
      for (int q = 0; q < 4; ++q) {
        int dl = reg * 32 + k8 * 8 + q * 2;
        pk[q] = (unsigned int)f32_to_bf16(tile[dl][hl]) |
                ((unsigned int)f32_to_bf16(tile[dl + 1][hl]) << 16);
      }
      size_t base = (((size_t)(e * 8 + nt) * 32 + kt) << 12) +
                    (size_t)(rbase + hl) * 32 + k8 * 8;
      *(uint4*)&Wf[base] = make_uint4(pk[0], pk[1], pk[2], pk[3]);
    }
    return;
  }
  // ---- gate scores: 4 tokens per wave ----
  const int blk  = bid - 2048;
  const int wave = threadIdx.x >> 6;
  const int lane = threadIdx.x & 63;
  const int tok0 = blk * 16 + wave * 4;

  float xs[4][16];
#pragma unroll
  for (int t = 0; t < 4; ++t) {
    const float* xr = x + (size_t)(tok0 + t) * DIM + lane * 16;
#pragma unroll
    for (int i = 0; i < 4; ++i)
      *(f32x4*)&xs[t][i * 4] = *(const f32x4*)(xr + i * 4);
  }
#pragma unroll
  for (int t = 0; t < 4; ++t) {
    unsigned int pk[8];
#pragma unroll
    for (int i = 0; i < 8; ++i)
      pk[i] = (unsigned int)f32_to_bf16(xs[t][2 * i]) |
              ((unsigned int)f32_to_bf16(xs[t][2 * i + 1]) << 16);
    uint4* xb = (uint4*)(Xbf + (size_t)(tok0 + t) * DIM + lane * 16);
    xb[0] = make_uint4(pk[0], pk[1], pk[2], pk[3]);
    xb[1] = make_uint4(pk[4], pk[5], pk[6], pk[7]);
  }

  double acc[4][8];
#pragma unroll
  for (int t = 0; t < 4; ++t)
#pragma unroll
    for (int e = 0; e < 8; ++e) acc[t][e] = 0.0;

  const float* wr = Wg + (size_t)(lane * 16) * NEXP;
#pragma unroll
  for (int i = 0; i < 16; ++i) {
    f32x4 wa = *(const f32x4*)(wr + i * 8);
    f32x4 wb = *(const f32x4*)(wr + i * 8 + 4);
    double w0 = wa[0], w1 = wa[1], w2 = wa[2], w3 = wa[3];
    double w4 = wb[0], w5 = wb[1], w6 = wb[2], w7 = wb[3];
#pragma unroll
    for (int t = 0; t < 4; ++t) {
      double xd = (double)xs[t][i];
      acc[t][0] += xd * w0; acc[t][1] += xd * w1;
      acc[t][2] += xd * w2; acc[t][3] += xd * w3;
      acc[t][4] += xd * w4; acc[t][5] += xd * w5;
      acc[t][6] += xd * w6; acc[t][7] += xd * w7;
    }
  }
#pragma unroll
  for (int m = 1; m < 64; m <<= 1)
#pragma unroll
    for (int t = 0; t < 4; ++t)
#pragma unroll
      for (int e = 0; e < 8; ++e) acc[t][e] += __shfl_xor(acc[t][e], m, 64);

  if (lane == 0) {
#pragma unroll
    for (int t = 0; t < 4; ++t) {
      float s[8];
#pragma unroll
      for (int e = 0; e < 8; ++e) s[e] = (float)acc[t][e] + bg[e];
      int i0 = 0; float v0 = s[0];
#pragma unroll
      for (int e = 1; e < 8; ++e) if (s[e] > v0) { v0 = s[e]; i0 = e; }
      int i1 = -1; float v1 = -3.4e38f;
#pragma unroll
      for (int e = 0; e < 8; ++e) if (e != i0 && s[e] > v1) { v1 = s[e]; i1 = e; }
      float t1 = expf(v1 - v0);
      float den = 1.0f + t1;
      tok_ee[tok0 + t] = i0 | (i1 << 8);
      tok_w[tok0 + t]  = make_float2(1.0f / den, t1 / den);
    }
  }
}

// ---------------------------------------------------------------------------
// Parallel deterministic compaction (unchanged).
// ---------------------------------------------------------------------------
__global__ __launch_bounds__(1024) void compact_kernel(
    const int* __restrict__ tok_ee, const float2* __restrict__ tok_w,
    int* __restrict__ counts, int* __restrict__ pair_token,
    float* __restrict__ pair_w) {
  __shared__ int wave_cnt[16];
  __shared__ int wave_off[16];
  const int e = blockIdx.x;
  const int tid = threadIdx.x, wave = tid >> 6, lane = tid & 63;
  int base = 0;
  for (int c = 0; c < NTOK / 1024; ++c) {
    const int t = c * 1024 + tid;
    const int p = tok_ee[t];
    const bool m0 = ((p & 255) == e);
    const bool m1 = (((p >> 8) & 255) == e);
    const unsigned long long m = __ballot(m0 || m1);
    const int pre = __popcll(m & ((1ull << lane) - 1ull));
    if (lane == 0) wave_cnt[wave] = __popcll(m);
    __syncthreads();
    if (tid == 0) {
      int s = base;
      for (int w = 0; w < 16; ++w) { wave_off[w] = s; s += wave_cnt[w]; }
      base = s;
    }
    __syncthreads();
    if (m0 || m1) {
      const float2 w = tok_w[t];
      const int slot = wave_off[wave] + pre;
      pair_token[e * MAXP + slot] = (t << 1) | (m1 ? 1 : 0);
      pair_w[e * MAXP + slot]     = m1 ? w.y : w.x;
    }
    __syncthreads();
  }
  if (tid == 0) counts[e] = base;
}

// ---------------------------------------------------------------------------
// Grouped GEMM — 256x256, BK=64, 8 waves, 4 phases per K-tile with m201-depth
// pipelining: one 2-load stage unit per phase, 3 half-tiles pre-staged in the
// prologue, vmcnt(8) twice per K-tile (keeps 4 units = 8 loads in flight,
// 5-phase issue->wait window). Phases split M (i-half), so ds_reads per
// phase are 8/4/8/4 and bfr[4] is reused across each phase pair.
// Ledger (units of 2 loads, issue order):
//   prologue: A(0,k0) B(0,k0) A(0,k1) B(0,k1) A(1,k0) B(1,k0); vmcnt(8)
//   iter t:  phA stage A(t+1,k1); phB stage B(t+1,k1), vmcnt(8) [frees (t,k1)]
//            phC stage A(t+2,k0); phD stage B(t+2,k0), vmcnt(8) [frees (t+1,k0)]
// Chunk swizzle (R1-proven 0-conflict): src chunk ^= (lane>>3)&3; read chunk
// = fq ^ ((fm>>1)&3). Stages target only dead slots (freed by the preceding
// phase barrier).
// ---------------------------------------------------------------------------
#define BARC()                                  \
  { asm volatile("" ::: "memory");              \
    __builtin_amdgcn_s_barrier();               \
    asm volatile("" ::: "memory"); }

__global__ __launch_bounds__(512, 2) void moe_gemm(
    const unsigned short* __restrict__ Xbf, const unsigned short* __restrict__ Wf,
    const float* __restrict__ be, const int* __restrict__ counts,
    const int* __restrict__ pair_token, const float* __restrict__ pair_w,
    _Float16* __restrict__ part, float* __restrict__ Y, int use_part) {
  const int id    = blockIdx.x;
  const int e     = id & 7;                 // expert -> XCD
  const int ntile = (id >> 3) & 3;          // 256-col tile
  const int m0    = (id >> 5) * 256;        // m-tile (0..9)
  const int cnt   = counts[e];
  if (m0 >= cnt) return;

  __shared__ __align__(16) unsigned short As[2][2][256 * 32];  // [buf][ks]
  __shared__ __align__(16) unsigned short Bs[2][2][256 * 32];

  const int tid  = threadIdx.x;
  const int wave = tid >> 6;                // 0..7
  const int lane = tid & 63;
  const int fm   = lane & 15;
  const int fq   = lane >> 4;
  const int wm   = wave >> 2;               // 0..1 (M half)
  const int wn   = wave & 3;                // 0..3 (N quarter)

  // staging source chunk swizzle (R1-proven, 0 conflicts)
  const int kc = (((lane & 3) ^ ((lane >> 3) & 3)) * 8);
  const unsigned short* gA[2];
  const unsigned short* gB[2];
#pragma unroll
  for (int l = 0; l < 2; ++l) {
    const int R  = wave * 2 + l;            // 16-row group 0..15
    const int gr = m0 + R * 16 + (lane >> 2);
    const int tk = (gr < cnt) ? (pair_token[e * MAXP + gr] >> 1) : 0;
    gA[l] = Xbf + (size_t)tk * DIM + kc;
    gB[l] = Wf + ((size_t)(e * 8 + ntile * 2 + (R >> 3)) << 17) +
            (size_t)((R & 7) * 16 + (lane >> 2)) * 32 + kc;
  }

  // one stage unit = 2 x 1KB lds-linear loads (A half-tile or B half-tile)
#define STAGE_A(buf, ksv, ttv)                                                \
  { _Pragma("unroll") for (int l = 0; l < 2; ++l)                             \
      __builtin_amdgcn_global_load_lds(                                       \
          (gas_ptr)(uintptr_t)(gA[l] + (ttv) * 64 + (ksv) * 32),              \
          (las_ptr)(uintptr_t)(&As[buf][ksv][(wave * 2 + l) * 512]), 16, 0, 0); }
#define STAGE_B(buf, ksv, ttv)                                                \
  { _Pragma("unroll") for (int l = 0; l < 2; ++l)                             \
      __builtin_amdgcn_global_load_lds(                                       \
          (gas_ptr)(uintptr_t)(gB[l] + (size_t)((ttv) * 2 + (ksv)) * 4096),   \
          (las_ptr)(uintptr_t)(&Bs[buf][ksv][(wave * 2 + l) * 512]), 16, 0, 0); }

  f32x4 acc[8][4];
#pragma unroll
  for (int i = 0; i < 8; ++i)
#pragma unroll
    for (int j = 0; j < 4; ++j) { f32x4 z = {0.f, 0.f, 0.f, 0.f}; acc[i][j] = z; }

  // swizzled ds_read chunk; row bases (row*32 elems, 64B rows)
  const int rdo  = (fq ^ ((fm >> 1) & 3)) * 8;
  const int arow = (wm * 128 + fm) * 32 + rdo;    // + i*512 (+2048 for i-hi)
  const int brow = (wn * 64 + fm) * 32 + rdo;     // + j*512

#define MFMA16(IB)                                                            \
  { _Pragma("unroll") for (int i = 0; i < 4; ++i)                             \
      _Pragma("unroll") for (int j = 0; j < 4; ++j)                           \
        acc[(IB) + i][j] = __builtin_amdgcn_mfma_f32_16x16x32_bf16(           \
            af[i], bfr[j], acc[(IB) + i][j], 0, 0, 0); }

  // prologue: 3 half-tiles pre-staged (t0 full + t1 ks0); keep newest 4 units
  STAGE_A(0, 0, 0); STAGE_B(0, 0, 0);
  STAGE_A(0, 1, 0); STAGE_B(0, 1, 0);
  STAGE_A(1, 0, 1); STAGE_B(1, 0, 1);
  asm volatile("s_waitcnt vmcnt(8)" ::: "memory");   // (t0,ks0) landed
  BARC();

#pragma unroll 2
  for (int t = 0; t < 16; ++t) {
    const int p  = t & 1;
    const int q  = p ^ 1;
    const int t1 = (t + 1) & 15;            // dummy re-stage near the tail
    const int t2 = (t + 2) & 15;
    bf16x8 af[4], bfr[4];

    // ---- phase A: ks0, M rows 0-63 ----
#pragma unroll
    for (int i = 0; i < 4; ++i) af[i] = *(const bf16x8*)&As[p][0][arow + i * 512];
#pragma unroll
    for (int j = 0; j < 4; ++j) bfr[j] = *(const bf16x8*)&Bs[p][0][brow + j * 512];
    STAGE_A(q, 1, t1);
    BARC();
    asm volatile("s_waitcnt lgkmcnt(0)" ::: "memory");
    __builtin_amdgcn_sched_barrier(0);
    __builtin_amdgcn_s_setprio(1);
    MFMA16(0);
    __builtin_amdgcn_s_setprio(0);
    BARC();

    // ---- phase B: ks0, M rows 64-127; vmcnt(8) frees (t,ks1) ----
#pragma unroll
    for (int i = 0; i < 4; ++i)
      af[i] = *(const bf16x8*)&As[p][0][arow + 2048 + i * 512];
    STAGE_B(q, 1, t1);
    BARC();
    asm volatile("s_waitcnt lgkmcnt(0)" ::: "memory");
    __builtin_amdgcn_sched_barrier(0);
    __builtin_amdgcn_s_setprio(1);
    MFMA16(4);
    __builtin_amdgcn_s_setprio(0);
    asm volatile("s_waitcnt vmcnt(8)" ::: "memory");
    BARC();

    // ---- phase C: ks1, M rows 0-63 ----
#pragma unroll
    for (int i = 0; i < 4; ++i) af[i] = *(const bf16x8*)&As[p][1][arow + i * 512];
#pragma unroll
    for (int j = 0; j < 4; ++j) bfr[j] = *(const bf16x8*)&Bs[p][1][brow + j * 512];
    STAGE_A(p, 0, t2);
    BARC();
    asm volatile("s_waitcnt lgkmcnt(0)" ::: "memory");
    __builtin_amdgcn_sched_barrier(0);
    __builtin_amdgcn_s_setprio(1);
    MFMA16(0);
    __builtin_amdgcn_s_setprio(0);
    BARC();

    // ---- phase D: ks1, M rows 64-127; vmcnt(8) frees (t+1,ks0) ----
#pragma unroll
    for (int i = 0; i < 4; ++i)
      af[i] = *(const bf16x8*)&As[p][1][arow + 2048 + i * 512];
    STAGE_B(p, 0, t2);
    BARC();
    asm volatile("s_waitcnt lgkmcnt(0)" ::: "memory");
    __builtin_amdgcn_sched_barrier(0);
    __builtin_amdgcn_s_setprio(1);
    MFMA16(4);
    __builtin_amdgcn_s_setprio(0);
    asm volatile("s_waitcnt vmcnt(8)" ::: "memory");
    BARC();
  }
  asm volatile("s_waitcnt vmcnt(0)" ::: "memory");    // drain dummy stages
#undef STAGE_A
#undef STAGE_B
#undef MFMA16

  // ---- epilogue ----
  int   rowv[8][4];
  float wrow[8][4];
#pragma unroll
  for (int i = 0; i < 8; ++i)
#pragma unroll
    for (int r = 0; r < 4; ++r) {
      int gr = m0 + wm * 128 + i * 16 + fq * 4 + r;
      bool valid = gr < cnt;
      rowv[i][r] = valid ? pair_token[e * MAXP + gr] : -1;
      wrow[i][r] = valid ? pair_w[e * MAXP + gr] : 0.f;
    }
  if (use_part) {
#pragma unroll
    for (int j = 0; j < 4; ++j) {
      int col = ntile * 256 + wn * 64 + j * 16 + fm;
      float bev = be[e * DIM + col];
#pragma unroll
      for (int i = 0; i < 8; ++i)
#pragma unroll
        for (int r = 0; r < 4; ++r) {
          int v = rowv[i][r];
          if (v >= 0)
            __builtin_nontemporal_store(
                (_Float16)(wrow[i][r] * (acc[i][j][r] + bev)),
                &part[(size_t)v * DIM + col]);
        }
    }
  } else {
#pragma unroll
    for (int j = 0; j < 4; ++j) {
      int col = ntile * 256 + wn * 64 + j * 16 + fm;
      float bev = be[e * DIM + col];
#pragma unroll
      for (int i = 0; i < 8; ++i)
#pragma unroll
        for (int r = 0; r < 4; ++r) {
          int v = rowv[i][r];
          if (v >= 0)
            atomicAdd(Y + (size_t)(v >> 1) * DIM + col,
                      wrow[i][r] * (acc[i][j][r] + bev));
        }
    }
  }
}

// ---------------------------------------------------------------------------
// Y[t][d] = part[2t][d] + part[2t+1][d]; fp16 in, fp32 out (unchanged).
// ---------------------------------------------------------------------------
__global__ __launch_bounds__(256) void reduce_pairs(
    const _Float16* __restrict__ part, float* __restrict__ Y) {
  const int g = blockIdx.x * 256 + threadIdx.x;
  const int t = g >> 7;
  const int o = (g & 127) * 8;
  const h16x8 a =
      __builtin_nontemporal_load((const h16x8*)(part + (size_t)(2 * t) * DIM + o));
  const h16x8 b =
      __builtin_nontemporal_load((const h16x8*)(part + (size_t)(2 * t + 1) * DIM + o));
  float* y = Y + (size_t)t * DIM + o;
  f32x4 lo = {(float)a[0] + (float)b[0], (float)a[1] + (float)b[1],
              (float)a[2] + (float)b[2], (float)a[3] + (float)b[3]};
  f32x4 hi = {(float)a[4] + (float)b[4], (float)a[5] + (float)b[5],
              (float)a[6] + (float)b[6], (float)a[7] + (float)b[7]};
  __builtin_nontemporal_store(lo, (f32x4*)y);
  __builtin_nontemporal_store(hi, (f32x4*)(y + 4));
}

// ---------------------------------------------------------------------------
extern "C" void kernel_launch(void* const* d_in, const int* in_sizes, int n_in,
                              void* d_out, int out_size, void* d_ws, size_t ws_size,
                              hipStream_t stream) {
  const float* x  = (const float*)d_in[0];
  const float* Wg = (const float*)d_in[1];
  const float* bg = (const float*)d_in[2];
  const float* We = (const float*)d_in[3];
  const float* be = (const float*)d_in[4];
  float* Y = (float*)d_out;

  const size_t MB = 1024 * 1024;
  char* ws = (char*)d_ws;
  unsigned short* Xbf = (unsigned short*)ws;                 // 16 MiB
  unsigned short* Wf  = (unsigned short*)(ws + 16 * MB);     // 16 MiB
  const size_t part_bytes = (size_t)NTOK * 2 * DIM * 2;      // 32 MiB (fp16)
  const size_t need = 32 * MB + part_bytes + 1 * MB;
  const int use_part = ws_size >= need;
  _Float16* part = (_Float16*)(ws + 32 * MB);
  char* p2 = ws + 32 * MB + (use_part ? part_bytes : 0);
  int*    counts     = (int*)p2;
  int*    pair_token = (int*)(p2 + 256);
  float*  pair_w     = (float*)(p2 + 256 + 262144);
  int*    tok_ee     = (int*)(p2 + 256 + 2 * 262144);
  float2* tok_w      = (float2*)(p2 + 256 + 2 * 262144 + 32768);

  if (!use_part)
    hipMemsetAsync(d_out, 0, (size_t)out_size * sizeof(float), stream);

  prep_kernel<<<2560, 256, 0, stream>>>(We, Wf, x, Wg, bg, Xbf, tok_ee, tok_w);
  compact_kernel<<<NEXP, 1024, 0, stream>>>(tok_ee, tok_w, counts, pair_token,
                                            pair_w);
  moe_gemm<<<8 * 4 * 10, 512, 0, stream>>>(
      Xbf, Wf, be, counts, pair_token, pair_w, part, Y, use_part);
  if (use_part)
    reduce_pairs<<<NTOK * DIM / 8 / 256, 256, 0, stream>>>(part, Y);
}